// Round 1
// baseline (526.962 us; speedup 1.0000x reference)
//
#include <hip/hip_runtime.h>
#include <hip/hip_bf16.h>

// Shapes: x1[8,256,128,128] f32, x2[8,128,256,256] f32, w1[1,256], b1[1], wt[2,2], bt[1]
// out[8,128,256,256] f32.
// K1: y[b,h,w] = sum_c x1[b,c,h,w]*w1[c] + b1        (y -> d_ws, 512 KiB)
// K2: up(i,j) = y[i>>1,j>>1]*wt[i&1,j&1] + bt  (reflect-padded on the fly)
//     3x3 joint bilateral (sigma=0.8 spatial+range, normalization cancels),
//     gate = sigmoid(filtered), out = x2*(1+gate)    (gate shared by 128 ch)

#define B     8
#define CIN   256
#define H     128
#define W     128
#define C2    128
#define HU    256
#define WU    256

__global__ __launch_bounds__(256) void conv1x1_kernel(
    const float* __restrict__ x1, const float* __restrict__ w1,
    const float* __restrict__ b1, float* __restrict__ y)
{
    __shared__ float wsh[CIN];
    int tid = threadIdx.x;
    wsh[tid] = w1[tid];
    __syncthreads();

    int t  = blockIdx.x * 256 + tid;          // 0 .. B*H*W-1  (131072)
    int b  = t >> 14;                          // / (H*W)
    int hw = t & 16383;

    const float* p = x1 + (size_t)b * CIN * H * W + hw;
    float acc = 0.f;
    #pragma unroll 8
    for (int c = 0; c < CIN; ++c)
        acc += p[(size_t)c * (H * W)] * wsh[c];
    y[t] = acc + b1[0];
}

__device__ __forceinline__ int refl(int i, int n) {
    // jnp.pad mode='reflect' (no edge repeat): -1 -> 1, n -> n-2
    return i < 0 ? -i : (i >= n ? 2 * n - 2 - i : i);
}

__global__ __launch_bounds__(256) void bilateral_gate_kernel(
    const float* __restrict__ y, const float* __restrict__ x2,
    const float* __restrict__ wt, const float* __restrict__ bt,
    float* __restrict__ out)
{
    int t   = blockIdx.x * 256 + threadIdx.x;  // 0 .. B*HU*(WU/4)-1  (131072)
    int wq  = t & 63;                           // quad index along wu
    int hu  = (t >> 6) & 255;
    int b   = t >> 14;
    int wu0 = wq * 4;

    const float* yb = y + (size_t)b * (H * W);
    float w2x2[4] = { wt[0], wt[1], wt[2], wt[3] };
    float btv = bt[0];

    // Build 3 rows x 6 cols of `up` covering the 4 pixels' 3x3 patches.
    float u[3][6];
    #pragma unroll
    for (int r = 0; r < 3; ++r) {
        int i  = refl(hu - 1 + r, HU);
        int iy = (i >> 1) * W;
        int ib = (i & 1) << 1;
        #pragma unroll
        for (int c = 0; c < 6; ++c) {
            int j = refl(wu0 - 1 + c, WU);
            u[r][c] = yb[iy + (j >> 1)] * w2x2[ib | (j & 1)] + btv;
        }
    }

    // sigma = 0.8 -> 1/(2*sigma^2) = 0.78125; unnormalized spatial kernel
    const float inv2s2 = 0.78125f;
    const float e1 = expf(-inv2s2);
    float k1v[3] = { e1, 1.f, e1 };

    float scale[4];
    #pragma unroll
    for (int p = 0; p < 4; ++p) {
        float ctr = u[1][p + 1];
        float num = 0.f, den = 0.f;
        #pragma unroll
        for (int r = 0; r < 3; ++r) {
            #pragma unroll
            for (int c = 0; c < 3; ++c) {
                float pv = u[r][p + c];
                float d  = pv - ctr;
                float w  = expf(-(d * d) * inv2s2) * (k1v[r] * k1v[c]);
                num += w * pv;
                den += w;
            }
        }
        float f = num / den;
        float g = 1.f / (1.f + expf(-f));      // sigmoid
        scale[p] = 1.f + g;                     // out = x2*(1+gate)
    }

    // 128 channels: float4 load/store, channel stride = HU*WU floats
    size_t base = (size_t)b * C2 * HU * WU + (size_t)hu * WU + wu0;
    const float4* xp = (const float4*)(x2 + base);
    float4*       op = (float4*)(out + base);
    const int cstride = HU * WU / 4;           // in float4 units

    #pragma unroll 4
    for (int c = 0; c < C2; ++c) {
        float4 v = xp[(size_t)c * cstride];
        v.x *= scale[0];
        v.y *= scale[1];
        v.z *= scale[2];
        v.w *= scale[3];
        op[(size_t)c * cstride] = v;
    }
}

extern "C" void kernel_launch(void* const* d_in, const int* in_sizes, int n_in,
                              void* d_out, int out_size, void* d_ws, size_t ws_size,
                              hipStream_t stream) {
    const float* x1 = (const float*)d_in[0];
    const float* x2 = (const float*)d_in[1];
    const float* w1 = (const float*)d_in[2];
    const float* b1 = (const float*)d_in[3];
    const float* wt = (const float*)d_in[4];
    const float* bt = (const float*)d_in[5];
    float* out = (float*)d_out;
    float* y   = (float*)d_ws;                 // 131072 floats = 512 KiB

    conv1x1_kernel<<<512, 256, 0, stream>>>(x1, w1, b1, y);
    bilateral_gate_kernel<<<512, 256, 0, stream>>>(y, x2, wt, bt, out);
}

// Round 2
// 524.109 us; speedup vs baseline: 1.0054x; 1.0054x over previous
//
#include <hip/hip_runtime.h>
#include <hip/hip_bf16.h>

// Shapes: x1[8,256,128,128] f32, x2[8,128,256,256] f32, w1[1,256], b1[1], wt[2,2], bt[1]
// out[8,128,256,256] f32.
// K1: y[b,h,w] = sum_c x1[b,c,h,w]*w1[c] + b1        (y -> d_ws, 512 KiB)
//     float4 over pixels, channels split 4-way across block, LDS reduce.
// K2: one block per (b,hu) row. Phase 1: 256 threads compute 256 gates -> LDS.
//     Phase 2: 64 float4-groups x 4 channel-chunks, 32 channels/thread stream.

#define B     8
#define CIN   256
#define H     128
#define W     128
#define C2    128
#define HU    256
#define WU    256

__global__ __launch_bounds__(256) void conv1x1_kernel(
    const float* __restrict__ x1, const float* __restrict__ w1,
    const float* __restrict__ b1, float* __restrict__ y)
{
    __shared__ float wsh[CIN];
    __shared__ float4 sred[256];
    int tid = threadIdx.x;
    wsh[tid] = w1[tid];
    __syncthreads();

    // block -> 256 consecutive pixels of batch b
    int b      = blockIdx.x >> 6;              // 64 blocks per batch image
    int hwbase = (blockIdx.x & 63) * 256;      // pixel offset within image

    int q  = tid & 63;                          // float4 pixel-group 0..63
    int cc = tid >> 6;                          // channel chunk 0..3 (64 ch each)

    const float4* p = (const float4*)(x1 + (size_t)b * CIN * H * W + hwbase) + q;
    const int cstride = H * W / 4;              // 4096 float4 per channel

    float4 acc = make_float4(0.f, 0.f, 0.f, 0.f);
    int c0 = cc * 64;
    #pragma unroll 8
    for (int k = 0; k < 64; ++k) {
        int c = c0 + k;
        float4 v = p[(size_t)c * cstride];
        float wv = wsh[c];
        acc.x += v.x * wv; acc.y += v.y * wv;
        acc.z += v.z * wv; acc.w += v.w * wv;
    }
    sred[tid] = acc;
    __syncthreads();

    if (cc == 0) {
        float4 a = sred[q], b2 = sred[q + 64], c2 = sred[q + 128], d2 = sred[q + 192];
        float bias = b1[0];
        float4 r;
        r.x = a.x + b2.x + c2.x + d2.x + bias;
        r.y = a.y + b2.y + c2.y + d2.y + bias;
        r.z = a.z + b2.z + c2.z + d2.z + bias;
        r.w = a.w + b2.w + c2.w + d2.w + bias;
        ((float4*)(y + (size_t)b * H * W + hwbase))[q] = r;
    }
}

__device__ __forceinline__ int refl(int i, int n) {
    // jnp.pad mode='reflect' (no edge repeat): -1 -> 1, n -> n-2
    return i < 0 ? -i : (i >= n ? 2 * n - 2 - i : i);
}

__global__ __launch_bounds__(256) void bilateral_gate_kernel(
    const float* __restrict__ y, const float* __restrict__ x2,
    const float* __restrict__ wt, const float* __restrict__ bt,
    float* __restrict__ out)
{
    __shared__ float scale_sh[WU];

    int hu = blockIdx.x & 255;
    int b  = blockIdx.x >> 8;
    int tid = threadIdx.x;

    // ---- Phase 1: gate for pixel (b, hu, tid) ----
    {
        int wu = tid;
        const float* yb = y + (size_t)b * (H * W);
        float w00 = wt[0], w01 = wt[1], w10 = wt[2], w11 = wt[3];
        float btv = bt[0];

        float u[3][3];
        #pragma unroll
        for (int r = 0; r < 3; ++r) {
            int i  = refl(hu - 1 + r, HU);
            int iy = (i >> 1) * W;
            float wr0 = (i & 1) ? w10 : w00;
            float wr1 = (i & 1) ? w11 : w01;
            #pragma unroll
            for (int c = 0; c < 3; ++c) {
                int j = refl(wu - 1 + c, WU);
                u[r][c] = yb[iy + (j >> 1)] * ((j & 1) ? wr1 : wr0) + btv;
            }
        }

        const float inv2s2 = 0.78125f;          // 1/(2*0.8^2)
        const float e1 = expf(-inv2s2);
        float k1v[3] = { e1, 1.f, e1 };

        float ctr = u[1][1];
        float num = 0.f, den = 0.f;
        #pragma unroll
        for (int r = 0; r < 3; ++r) {
            #pragma unroll
            for (int c = 0; c < 3; ++c) {
                float pv = u[r][c];
                float d  = pv - ctr;
                float w  = expf(-(d * d) * inv2s2) * (k1v[r] * k1v[c]);
                num += w * pv;
                den += w;
            }
        }
        float f = num / den;
        float g = 1.f / (1.f + expf(-f));
        scale_sh[wu] = 1.f + g;                 // out = x2 * (1 + gate)
    }
    __syncthreads();

    // ---- Phase 2: stream 128 channels, split 4-way ----
    int g  = tid & 63;                           // float4 group along wu
    int cc = tid >> 6;                           // channel chunk 0..3
    float4 sc = ((const float4*)scale_sh)[g];    // invariant across channels

    size_t base = (size_t)b * C2 * HU * WU + (size_t)hu * WU + (size_t)g * 4;
    const int cstride = HU * WU / 4;             // float4 units
    const float4* xp = (const float4*)(x2 + base) + (size_t)(cc * 32) * cstride;
    float4*       op = (float4*)(out + base)     + (size_t)(cc * 32) * cstride;

    #pragma unroll 8
    for (int k = 0; k < 32; ++k) {
        float4 v = xp[(size_t)k * cstride];
        v.x *= sc.x; v.y *= sc.y; v.z *= sc.z; v.w *= sc.w;
        op[(size_t)k * cstride] = v;
    }
}

extern "C" void kernel_launch(void* const* d_in, const int* in_sizes, int n_in,
                              void* d_out, int out_size, void* d_ws, size_t ws_size,
                              hipStream_t stream) {
    const float* x1 = (const float*)d_in[0];
    const float* x2 = (const float*)d_in[1];
    const float* w1 = (const float*)d_in[2];
    const float* b1 = (const float*)d_in[3];
    const float* wt = (const float*)d_in[4];
    const float* bt = (const float*)d_in[5];
    float* out = (float*)d_out;
    float* y   = (float*)d_ws;                 // 131072 floats = 512 KiB

    conv1x1_kernel<<<512, 256, 0, stream>>>(x1, w1, b1, y);
    bilateral_gate_kernel<<<B * HU, 256, 0, stream>>>(y, x2, wt, bt, out);
}